// Round 1
// baseline (2969.050 us; speedup 1.0000x reference)
//
#include <hip/hip_runtime.h>
#include <hip/hip_bf16.h>

#define T_TOK 2048
#define HDIM  2048
#define IDIM  1024
#define NE    16
#define NEX   17   // 16 routed + 1 shared
#define NASSIGN (T_TOK*2 + T_TOK)   // 6144 rows: 4096 routed + 2048 shared

__device__ __forceinline__ unsigned short f2bf(float f) {
    union { float f; unsigned u; } v; v.f = f;
    unsigned r = v.u + 0x7fffu + ((v.u >> 16) & 1u);   // RNE
    return (unsigned short)(r >> 16);
}
__device__ __forceinline__ float bf2f(unsigned short h) {
    return __uint_as_float(((unsigned)h) << 16);
}

// ---------------- Router: logits -> softmax -> top2 -> weights ----------------
__global__ void k_router(const float* __restrict__ x, const float* __restrict__ Wr,
                         const float* __restrict__ bias, float* __restrict__ wtok,
                         int* __restrict__ idxtok, int* __restrict__ counts) {
    int t = blockIdx.x;
    int lane = threadIdx.x & 63;
    int wave = threadIdx.x >> 6;
    __shared__ float lg[NE];
    const float4* xr = (const float4*)(x + (size_t)t * HDIM);
    for (int e = wave; e < NE; e += 4) {
        const float4* wr = (const float4*)(Wr + (size_t)e * HDIM);
        float s = 0.f;
        for (int j = lane; j < HDIM / 4; j += 64) {
            float4 a = xr[j], b = wr[j];
            s += a.x*b.x + a.y*b.y + a.z*b.z + a.w*b.w;
        }
        #pragma unroll
        for (int d = 32; d; d >>= 1) s += __shfl_xor(s, d);
        if (lane == 0) lg[e] = s + bias[e];
    }
    __syncthreads();
    if (threadIdx.x == 0) {
        float m = lg[0];
        #pragma unroll
        for (int e = 1; e < NE; e++) m = fmaxf(m, lg[e]);
        float p[NE]; float S = 0.f;
        #pragma unroll
        for (int e = 0; e < NE; e++) { p[e] = expf(lg[e] - m); S += p[e]; }
        int i0 = 0;
        #pragma unroll
        for (int e = 1; e < NE; e++) if (p[e] > p[i0]) i0 = e;
        int i1 = (i0 == 0) ? 1 : 0;
        for (int e = 0; e < NE; e++) if (e != i0 && p[e] > p[i1]) i1 = e;
        float v0 = p[i0] / S, v1 = p[i1] / S;
        float wsum = v0 + v1 + 1e-9f;
        wtok[t*2+0] = v0 / wsum;
        wtok[t*2+1] = v1 / wsum;
        idxtok[t*2+0] = i0;
        idxtok[t*2+1] = i1;
        atomicAdd(&counts[i0], 1);
        atomicAdd(&counts[i1], 1);
    }
}

// ---------------- Prefix-sum over 17 experts ----------------
__global__ void k_scan(const int* __restrict__ counts, int* __restrict__ offs,
                       int* __restrict__ cursor) {
    if (threadIdx.x == 0) {
        int acc = 0;
        for (int e = 0; e < NEX; e++) {
            offs[e] = acc; cursor[e] = acc;
            acc += (e < NE) ? counts[e] : T_TOK;
        }
        offs[NEX] = acc;
    }
}

// ---------------- Scatter tokens into per-expert lists ----------------
__global__ void k_scatter(const int* __restrict__ idxtok, const float* __restrict__ wtok,
                          int* __restrict__ cursor, const int* __restrict__ offs,
                          int* __restrict__ rows, float* __restrict__ wrow) {
    int t = blockIdx.x * blockDim.x + threadIdx.x;
    if (t >= T_TOK) return;
    #pragma unroll
    for (int k = 0; k < 2; k++) {
        int e = idxtok[t*2+k];
        int pos = atomicAdd(&cursor[e], 1);
        rows[pos] = t;
        wrow[pos] = wtok[t*2+k];
    }
    int p16 = offs[NE] + t;   // shared expert: identity list
    rows[p16] = t;
    wrow[p16] = 1.0f;
}

// ---------------- GEMM1: act = w * silu(X@Wg) * (X@Wu), bf16 out ----------------
// grid: (IDIM/128, 64, 17), block 256. Tile: 32 rows x 128 cols.
__global__ __launch_bounds__(256) void k_gemm1(
        const float* __restrict__ x,
        const float* __restrict__ Wg, const float* __restrict__ Wu,
        const float* __restrict__ sWg, const float* __restrict__ sWu,
        const int* __restrict__ offs, const int* __restrict__ rows,
        const float* __restrict__ wrow, unsigned short* __restrict__ act) {
    int e = blockIdx.z;
    int rs = offs[e] + blockIdx.y * 32;
    int re = offs[e+1];
    if (rs >= re) return;
    int nrows = min(32, re - rs);
    const float* wg = (e < NE) ? Wg + (size_t)e * HDIM * IDIM : sWg;
    const float* wu = (e < NE) ? Wu + (size_t)e * HDIM * IDIM : sWu;
    int n0 = blockIdx.x * 128;
    int tid = threadIdx.x;
    int n  = tid & 63;
    int mg = tid >> 6;          // 0..3 -> rows mg*8..mg*8+7
    int lm = tid >> 3;          // load row 0..31
    int lk = (tid & 7) * 4;     // load col 0..28

    __shared__ float xs[32][36];
    __shared__ int rloc[32];
    if (tid < 32) rloc[tid] = rows[rs + min(tid, nrows - 1)];
    __syncthreads();

    float ag0[8] = {0}, ag1[8] = {0}, au0[8] = {0}, au1[8] = {0};

    for (int k0 = 0; k0 < HDIM; k0 += 32) {
        float4 xv = *(const float4*)(x + (size_t)rloc[lm] * HDIM + k0 + lk);
        __syncthreads();
        *(float4*)&xs[lm][lk] = xv;
        __syncthreads();
        #pragma unroll 2
        for (int kk4 = 0; kk4 < 8; kk4++) {
            float wg0[4], wg1[4], wu0[4], wu1[4];
            #pragma unroll
            for (int j = 0; j < 4; j++) {
                size_t roff = (size_t)(k0 + kk4*4 + j) * IDIM + n0 + n;
                wg0[j] = wg[roff];      wg1[j] = wg[roff + 64];
                wu0[j] = wu[roff];      wu1[j] = wu[roff + 64];
            }
            #pragma unroll
            for (int m8 = 0; m8 < 8; m8++) {
                float4 xq = *(const float4*)&xs[mg*8 + m8][kk4*4];
                ag0[m8] = fmaf(xq.x, wg0[0], fmaf(xq.y, wg0[1], fmaf(xq.z, wg0[2], fmaf(xq.w, wg0[3], ag0[m8]))));
                ag1[m8] = fmaf(xq.x, wg1[0], fmaf(xq.y, wg1[1], fmaf(xq.z, wg1[2], fmaf(xq.w, wg1[3], ag1[m8]))));
                au0[m8] = fmaf(xq.x, wu0[0], fmaf(xq.y, wu0[1], fmaf(xq.z, wu0[2], fmaf(xq.w, wu0[3], au0[m8]))));
                au1[m8] = fmaf(xq.x, wu1[0], fmaf(xq.y, wu1[1], fmaf(xq.z, wu1[2], fmaf(xq.w, wu1[3], au1[m8]))));
            }
        }
    }

    #pragma unroll
    for (int m8 = 0; m8 < 8; m8++) {
        int m = mg*8 + m8;
        if (m < nrows) {
            float wv = wrow[rs + m];
            float g0 = ag0[m8], g1 = ag1[m8];
            float a0 = g0 / (1.f + expf(-g0)) * au0[m8] * wv;
            float a1 = g1 / (1.f + expf(-g1)) * au1[m8] * wv;
            size_t base = (size_t)(rs + m) * IDIM + n0 + n;
            act[base]      = f2bf(a0);
            act[base + 64] = f2bf(a1);
        }
    }
}

// ---------------- GEMM2: out[t] += act @ Wd ----------------
// grid: (HDIM/128, 64, 17), block 256. Tile: 32 rows x 128 cols.
__global__ __launch_bounds__(256) void k_gemm2(
        const unsigned short* __restrict__ act,
        const float* __restrict__ Wd, const float* __restrict__ sWd,
        const int* __restrict__ offs, const int* __restrict__ rows,
        float* __restrict__ out) {
    int e = blockIdx.z;
    int rs = offs[e] + blockIdx.y * 32;
    int re = offs[e+1];
    if (rs >= re) return;
    int nrows = min(32, re - rs);
    const float* wd = (e < NE) ? Wd + (size_t)e * IDIM * HDIM : sWd;
    int n0 = blockIdx.x * 128;
    int tid = threadIdx.x;
    int n  = tid & 63;
    int mg = tid >> 6;
    int lm = tid >> 3;
    int lk = (tid & 7) * 4;

    __shared__ float as[32][36];
    __shared__ int rloc[32];
    if (tid < 32) rloc[tid] = rows[rs + min(tid, nrows - 1)];

    float ac0[8] = {0}, ac1[8] = {0};
    int arow = rs + min(lm, nrows - 1);

    for (int k0 = 0; k0 < IDIM; k0 += 32) {
        ushort4 av = *(const ushort4*)(act + (size_t)arow * IDIM + k0 + lk);
        __syncthreads();
        as[lm][lk+0] = bf2f(av.x);
        as[lm][lk+1] = bf2f(av.y);
        as[lm][lk+2] = bf2f(av.z);
        as[lm][lk+3] = bf2f(av.w);
        __syncthreads();
        #pragma unroll 2
        for (int kk4 = 0; kk4 < 8; kk4++) {
            float wd0[4], wd1[4];
            #pragma unroll
            for (int j = 0; j < 4; j++) {
                size_t roff = (size_t)(k0 + kk4*4 + j) * HDIM + n0 + n;
                wd0[j] = wd[roff];
                wd1[j] = wd[roff + 64];
            }
            #pragma unroll
            for (int m8 = 0; m8 < 8; m8++) {
                float4 aq = *(const float4*)&as[mg*8 + m8][kk4*4];
                ac0[m8] = fmaf(aq.x, wd0[0], fmaf(aq.y, wd0[1], fmaf(aq.z, wd0[2], fmaf(aq.w, wd0[3], ac0[m8]))));
                ac1[m8] = fmaf(aq.x, wd1[0], fmaf(aq.y, wd1[1], fmaf(aq.z, wd1[2], fmaf(aq.w, wd1[3], ac1[m8]))));
            }
        }
    }

    #pragma unroll
    for (int m8 = 0; m8 < 8; m8++) {
        int m = mg*8 + m8;
        if (m < nrows) {
            size_t base = (size_t)rloc[m] * HDIM + n0 + n;
            atomicAdd(&out[base],      ac0[m8]);
            atomicAdd(&out[base + 64], ac1[m8]);
        }
    }
}

extern "C" void kernel_launch(void* const* d_in, const int* in_sizes, int n_in,
                              void* d_out, int out_size, void* d_ws, size_t ws_size,
                              hipStream_t stream) {
    const float* x    = (const float*)d_in[0];
    const float* Wr   = (const float*)d_in[1];
    const float* bias = (const float*)d_in[2];
    const float* Wg   = (const float*)d_in[3];
    const float* Wu   = (const float*)d_in[4];
    const float* Wd   = (const float*)d_in[5];
    const float* sWg  = (const float*)d_in[6];
    const float* sWu  = (const float*)d_in[7];
    const float* sWd  = (const float*)d_in[8];
    float* out = (float*)d_out;

    char* p = (char*)d_ws;
    int*   counts = (int*)p;                 p += 256;
    int*   offs   = (int*)p;                 p += 256;
    int*   cursor = (int*)p;                 p += 256;
    int*   idxtok = (int*)p;                 p += (size_t)T_TOK * 2 * sizeof(int);
    float* wtok   = (float*)p;               p += (size_t)T_TOK * 2 * sizeof(float);
    int*   rows   = (int*)p;                 p += (size_t)NASSIGN * sizeof(int);
    float* wrow   = (float*)p;               p += (size_t)NASSIGN * sizeof(float);
    unsigned short* act = (unsigned short*)p;  // NASSIGN * IDIM bf16 = 12.6 MB

    hipMemsetAsync(counts, 0, 256, stream);
    hipMemsetAsync(d_out, 0, (size_t)out_size * sizeof(float), stream);

    k_router<<<dim3(T_TOK), dim3(256), 0, stream>>>(x, Wr, bias, wtok, idxtok, counts);
    k_scan<<<dim3(1), dim3(64), 0, stream>>>(counts, offs, cursor);
    k_scatter<<<dim3((T_TOK + 255) / 256), dim3(256), 0, stream>>>(idxtok, wtok, cursor, offs, rows, wrow);
    k_gemm1<<<dim3(IDIM / 128, 64, NEX), dim3(256), 0, stream>>>(x, Wg, Wu, sWg, sWu, offs, rows, wrow, act);
    k_gemm2<<<dim3(HDIM / 128, 64, NEX), dim3(256), 0, stream>>>(act, Wd, sWd, offs, rows, out);
}

// Round 2
// 1209.537 us; speedup vs baseline: 2.4547x; 2.4547x over previous
//
#include <hip/hip_runtime.h>
#include <hip/hip_bf16.h>

#define T_TOK 2048
#define HDIM  2048
#define IDIM  1024
#define NE    16
#define NEX   17   // 16 routed + 1 shared
#define NASSIGN (T_TOK*3)   // 4096 routed + 2048 shared assignment slots

typedef __attribute__((ext_vector_type(8))) short bf16x8;   // 8 bf16 (4 VGPRs)
typedef __attribute__((ext_vector_type(4))) float f32x4;    // MFMA acc

__device__ __forceinline__ unsigned short f2bf(float f) {
    union { float f; unsigned u; } v; v.f = f;
    unsigned r = v.u + 0x7fffu + ((v.u >> 16) & 1u);   // RNE
    return (unsigned short)(r >> 16);
}
__device__ __forceinline__ unsigned pack2(float a, float b) {
    return (unsigned)f2bf(a) | ((unsigned)f2bf(b) << 16);
}
__device__ __forceinline__ float fidx(const float4& v, int j) {
    return ((const float*)&v)[j];
}
// XOR swizzle for [row][64 bf16] (128B) LDS rows: spreads 16B slots so both
// fragment ds_read_b128 (lanes = 16 consecutive rows) and staging writes are <=2-way.
__device__ __forceinline__ int swz(int row, int byteoff) {
    return byteoff ^ (((row ^ (row >> 2)) & 7) << 4);
}
__device__ __forceinline__ bf16x8 lds_frag(const unsigned short* b, int row, int k) {
    return *(const bf16x8*)((const char*)b + swz(row, (row << 7) + (k << 1)));
}
__device__ __forceinline__ f32x4 mfma16(bf16x8 a, bf16x8 b, f32x4 c) {
    return __builtin_amdgcn_mfma_f32_16x16x32_bf16(a, b, c, 0, 0, 0);
}

// ---------------- Router: logits -> softmax -> top2 -> weights ----------------
__global__ void k_router(const float* __restrict__ x, const float* __restrict__ Wr,
                         const float* __restrict__ bias, float* __restrict__ wtok,
                         int* __restrict__ idxtok, int* __restrict__ counts) {
    int t = blockIdx.x;
    int lane = threadIdx.x & 63;
    int wave = threadIdx.x >> 6;
    __shared__ float lg[NE];
    const float4* xr = (const float4*)(x + (size_t)t * HDIM);
    for (int e = wave; e < NE; e += 4) {
        const float4* wr = (const float4*)(Wr + (size_t)e * HDIM);
        float s = 0.f;
        for (int j = lane; j < HDIM / 4; j += 64) {
            float4 a = xr[j], b = wr[j];
            s += a.x*b.x + a.y*b.y + a.z*b.z + a.w*b.w;
        }
        #pragma unroll
        for (int d = 32; d; d >>= 1) s += __shfl_xor(s, d);
        if (lane == 0) lg[e] = s + bias[e];
    }
    __syncthreads();
    if (threadIdx.x == 0) {
        float m = lg[0];
        #pragma unroll
        for (int e = 1; e < NE; e++) m = fmaxf(m, lg[e]);
        float p[NE]; float S = 0.f;
        #pragma unroll
        for (int e = 0; e < NE; e++) { p[e] = expf(lg[e] - m); S += p[e]; }
        int i0 = 0;
        #pragma unroll
        for (int e = 1; e < NE; e++) if (p[e] > p[i0]) i0 = e;
        int i1 = (i0 == 0) ? 1 : 0;
        for (int e = 0; e < NE; e++) if (e != i0 && p[e] > p[i1]) i1 = e;
        float v0 = p[i0] / S, v1 = p[i1] / S;
        float wsum = v0 + v1 + 1e-9f;
        wtok[t*2+0] = v0 / wsum;
        wtok[t*2+1] = v1 / wsum;
        idxtok[t*2+0] = i0;
        idxtok[t*2+1] = i1;
        atomicAdd(&counts[i0], 1);
        atomicAdd(&counts[i1], 1);
    }
}

__global__ void k_scan(const int* __restrict__ counts, int* __restrict__ offs,
                       int* __restrict__ cursor) {
    if (threadIdx.x == 0) {
        int acc = 0;
        for (int e = 0; e < NEX; e++) {
            offs[e] = acc; cursor[e] = acc;
            acc += (e < NE) ? counts[e] : T_TOK;
        }
        offs[NEX] = acc;
    }
}

__global__ void k_scatter(const int* __restrict__ idxtok, const float* __restrict__ wtok,
                          int* __restrict__ cursor, const int* __restrict__ offs,
                          int* __restrict__ rows, float* __restrict__ wrow) {
    int t = blockIdx.x * blockDim.x + threadIdx.x;
    if (t >= T_TOK) return;
    #pragma unroll
    for (int k = 0; k < 2; k++) {
        int e = idxtok[t*2+k];
        int pos = atomicAdd(&cursor[e], 1);
        rows[pos] = t;
        wrow[pos] = wtok[t*2+k];
    }
    int p16 = offs[NE] + t;   // shared expert: identity list, weight 1
    rows[p16] = t;
    wrow[p16] = 1.0f;
}

// ---------------- GEMM1 (MFMA): act = w * silu(X@Wg) * (X@Wu), bf16 out --------
// grid: (32 row-tiles, IDIM/64 col-tiles, 17 experts), block 256 = 4 waves (2x2).
__global__ __launch_bounds__(256) void k_gemm1(
        const float* __restrict__ x,
        const float* __restrict__ Wg, const float* __restrict__ Wu,
        const float* __restrict__ sWg, const float* __restrict__ sWu,
        const int* __restrict__ offs, const int* __restrict__ rows,
        const float* __restrict__ wrow, unsigned short* __restrict__ act) {
    int e = blockIdx.z;
    int rs = offs[e] + blockIdx.x * 64;
    int re = offs[e + 1];
    if (rs >= re) return;
    int nrows = min(64, re - rs);
    const float* wg = (e < NE) ? Wg + (size_t)e * HDIM * IDIM : sWg;
    const float* wu = (e < NE) ? Wu + (size_t)e * HDIM * IDIM : sWu;
    int n0 = blockIdx.y * 64;

    __shared__ unsigned short xs[64 * 64];   // [row][k] bf16, swizzled, 8KB
    __shared__ unsigned short gs[64 * 64];   // [n][k]  (W^T), swizzled
    __shared__ unsigned short us[64 * 64];
    __shared__ int rloc[64];

    int tid = threadIdx.x;
    if (tid < 64) rloc[tid] = rows[rs + min(tid, nrows - 1)];
    __syncthreads();

    // staging coords
    int xrow = tid >> 2;                 // 0..63
    int xk   = (tid & 3) << 4;           // 0,16,32,48
    const float* xp = x + (size_t)rloc[xrow] * HDIM + xk;
    int wn = (tid & 15) << 2;            // 0..60
    int wk = (tid >> 4) << 1;            // 0,2,..,30 (and +32 pair)
    const float* gp = wg + (size_t)wk * IDIM + n0 + wn;
    const float* up = wu + (size_t)wk * IDIM + n0 + wn;

    int lane = tid & 63;
    int wv = tid >> 6;
    int wr = (wv >> 1) << 5;             // wave row offset 0/32
    int wc = (wv & 1) << 5;              // wave col offset 0/32
    int fr = lane & 15;
    int fk = (lane >> 4) << 3;           // k element offset 0/8/16/24

    f32x4 ag[2][2] = {}, au[2][2] = {};

    for (int k0 = 0; k0 < HDIM; k0 += 64) {
        // issue global loads (overlap with previous tile's MFMA until barrier)
        float4 xv0 = *(const float4*)(xp + k0);
        float4 xv1 = *(const float4*)(xp + k0 + 4);
        float4 xv2 = *(const float4*)(xp + k0 + 8);
        float4 xv3 = *(const float4*)(xp + k0 + 12);
        const float* g0p = gp + (size_t)k0 * IDIM;
        float4 gv0 = *(const float4*)(g0p);
        float4 gv1 = *(const float4*)(g0p + IDIM);
        float4 gv2 = *(const float4*)(g0p + (size_t)32 * IDIM);
        float4 gv3 = *(const float4*)(g0p + (size_t)33 * IDIM);
        const float* u0p = up + (size_t)k0 * IDIM;
        float4 uv0 = *(const float4*)(u0p);
        float4 uv1 = *(const float4*)(u0p + IDIM);
        float4 uv2 = *(const float4*)(u0p + (size_t)32 * IDIM);
        float4 uv3 = *(const float4*)(u0p + (size_t)33 * IDIM);

        __syncthreads();   // previous tile fully consumed

        {   // X tile: 16 bf16 per thread, two ds_write_b128
            int bo = (xrow << 7) + (xk << 1);
            uint4 w0, w1;
            w0.x = pack2(xv0.x, xv0.y); w0.y = pack2(xv0.z, xv0.w);
            w0.z = pack2(xv1.x, xv1.y); w0.w = pack2(xv1.z, xv1.w);
            w1.x = pack2(xv2.x, xv2.y); w1.y = pack2(xv2.z, xv2.w);
            w1.z = pack2(xv3.x, xv3.y); w1.w = pack2(xv3.z, xv3.w);
            *(uint4*)((char*)xs + swz(xrow, bo)) = w0;
            *(uint4*)((char*)xs + swz(xrow, bo + 16)) = w1;
        }
        #pragma unroll
        for (int j = 0; j < 4; ++j) {   // W^T writes: k-pairs packed as b32
            int n = wn + j;
            int bo = (n << 7) + (wk << 1);
            *(unsigned*)((char*)gs + swz(n, bo))      = pack2(fidx(gv0,j), fidx(gv1,j));
            *(unsigned*)((char*)gs + swz(n, bo + 64)) = pack2(fidx(gv2,j), fidx(gv3,j));
            *(unsigned*)((char*)us + swz(n, bo))      = pack2(fidx(uv0,j), fidx(uv1,j));
            *(unsigned*)((char*)us + swz(n, bo + 64)) = pack2(fidx(uv2,j), fidx(uv3,j));
        }
        __syncthreads();   // tile ready

        #pragma unroll
        for (int kh = 0; kh < 2; ++kh) {
            int kk = (kh << 5) + fk;
            bf16x8 a0  = lds_frag(xs, wr + fr, kk);
            bf16x8 a1  = lds_frag(xs, wr + 16 + fr, kk);
            bf16x8 bg0 = lds_frag(gs, wc + fr, kk);
            bf16x8 bg1 = lds_frag(gs, wc + 16 + fr, kk);
            bf16x8 bu0 = lds_frag(us, wc + fr, kk);
            bf16x8 bu1 = lds_frag(us, wc + 16 + fr, kk);
            ag[0][0] = mfma16(a0, bg0, ag[0][0]);
            ag[0][1] = mfma16(a0, bg1, ag[0][1]);
            ag[1][0] = mfma16(a1, bg0, ag[1][0]);
            ag[1][1] = mfma16(a1, bg1, ag[1][1]);
            au[0][0] = mfma16(a0, bu0, au[0][0]);
            au[0][1] = mfma16(a0, bu1, au[0][1]);
            au[1][0] = mfma16(a1, bu0, au[1][0]);
            au[1][1] = mfma16(a1, bu1, au[1][1]);
        }
    }

    // epilogue: SwiGLU * routing weight -> bf16 act
    int crow = (lane >> 4) << 2;
    int ccol = lane & 15;
    #pragma unroll
    for (int mf = 0; mf < 2; ++mf) {
        #pragma unroll
        for (int reg = 0; reg < 4; ++reg) {
            int r = wr + (mf << 4) + crow + reg;
            if (r < nrows) {
                float wvv = wrow[rs + r];
                size_t base = (size_t)(rs + r) * IDIM + n0 + wc + ccol;
                #pragma unroll
                for (int nf = 0; nf < 2; ++nf) {
                    float g = ag[mf][nf][reg];
                    float u = au[mf][nf][reg];
                    float a = g / (1.f + expf(-g)) * u * wvv;
                    act[base + nf * 16] = f2bf(a);
                }
            }
        }
    }
}

// ---------------- GEMM2 (MFMA): out[tok] += act @ Wd ----------------
// grid: (32 row-tiles, HDIM/64 col-tiles, 17 experts), block 256 = 4 waves.
__global__ __launch_bounds__(256) void k_gemm2(
        const unsigned short* __restrict__ act,
        const float* __restrict__ Wd, const float* __restrict__ sWd,
        const int* __restrict__ offs, const int* __restrict__ rows,
        float* __restrict__ out) {
    int e = blockIdx.z;
    int rs = offs[e] + blockIdx.x * 64;
    int re = offs[e + 1];
    if (rs >= re) return;
    int nrows = min(64, re - rs);
    const float* wd = (e < NE) ? Wd + (size_t)e * IDIM * HDIM : sWd;
    int n0 = blockIdx.y * 64;

    __shared__ unsigned short as_[64 * 64];
    __shared__ unsigned short ws_[64 * 64];
    __shared__ int rloc[64];

    int tid = threadIdx.x;
    if (tid < 64) rloc[tid] = rows[rs + min(tid, nrows - 1)];

    int arow = tid >> 2;
    int ak = (tid & 3) << 4;
    const unsigned short* ap = act + (size_t)(rs + min(arow, nrows - 1)) * IDIM + ak;
    int wn = (tid & 15) << 2;
    int wk = (tid >> 4) << 1;
    const float* dp = wd + (size_t)wk * HDIM + n0 + wn;

    int lane = tid & 63;
    int wv = tid >> 6;
    int wr = (wv >> 1) << 5;
    int wc = (wv & 1) << 5;
    int fr = lane & 15;
    int fk = (lane >> 4) << 3;

    f32x4 acc[2][2] = {};

    for (int k0 = 0; k0 < IDIM; k0 += 64) {
        uint4 av0 = *(const uint4*)(ap + k0);
        uint4 av1 = *(const uint4*)(ap + k0 + 8);
        const float* d0p = dp + (size_t)k0 * HDIM;
        float4 dv0 = *(const float4*)(d0p);
        float4 dv1 = *(const float4*)(d0p + HDIM);
        float4 dv2 = *(const float4*)(d0p + (size_t)32 * HDIM);
        float4 dv3 = *(const float4*)(d0p + (size_t)33 * HDIM);

        __syncthreads();
        {
            int bo = (arow << 7) + (ak << 1);
            *(uint4*)((char*)as_ + swz(arow, bo)) = av0;
            *(uint4*)((char*)as_ + swz(arow, bo + 16)) = av1;
        }
        #pragma unroll
        for (int j = 0; j < 4; ++j) {
            int n = wn + j;
            int bo = (n << 7) + (wk << 1);
            *(unsigned*)((char*)ws_ + swz(n, bo))      = pack2(fidx(dv0,j), fidx(dv1,j));
            *(unsigned*)((char*)ws_ + swz(n, bo + 64)) = pack2(fidx(dv2,j), fidx(dv3,j));
        }
        __syncthreads();

        #pragma unroll
        for (int kh = 0; kh < 2; ++kh) {
            int kk = (kh << 5) + fk;
            bf16x8 a0 = lds_frag(as_, wr + fr, kk);
            bf16x8 a1 = lds_frag(as_, wr + 16 + fr, kk);
            bf16x8 b0 = lds_frag(ws_, wc + fr, kk);
            bf16x8 b1 = lds_frag(ws_, wc + 16 + fr, kk);
            acc[0][0] = mfma16(a0, b0, acc[0][0]);
            acc[0][1] = mfma16(a0, b1, acc[0][1]);
            acc[1][0] = mfma16(a1, b0, acc[1][0]);
            acc[1][1] = mfma16(a1, b1, acc[1][1]);
        }
    }

    int crow = (lane >> 4) << 2;
    int ccol = lane & 15;
    #pragma unroll
    for (int mf = 0; mf < 2; ++mf) {
        #pragma unroll
        for (int reg = 0; reg < 4; ++reg) {
            int r = wr + (mf << 4) + crow + reg;
            if (r < nrows) {
                size_t base = (size_t)rloc[r] * HDIM + n0 + wc + ccol;
                atomicAdd(&out[base],      acc[mf][0][reg]);
                atomicAdd(&out[base + 16], acc[mf][1][reg]);
            }
        }
    }
}

extern "C" void kernel_launch(void* const* d_in, const int* in_sizes, int n_in,
                              void* d_out, int out_size, void* d_ws, size_t ws_size,
                              hipStream_t stream) {
    const float* x    = (const float*)d_in[0];
    const float* Wr   = (const float*)d_in[1];
    const float* bias = (const float*)d_in[2];
    const float* Wg   = (const float*)d_in[3];
    const float* Wu   = (const float*)d_in[4];
    const float* Wd   = (const float*)d_in[5];
    const float* sWg  = (const float*)d_in[6];
    const float* sWu  = (const float*)d_in[7];
    const float* sWd  = (const float*)d_in[8];
    float* out = (float*)d_out;

    char* p = (char*)d_ws;
    int*   counts = (int*)p;                 p += 256;
    int*   offs   = (int*)p;                 p += 256;
    int*   cursor = (int*)p;                 p += 256;
    int*   idxtok = (int*)p;                 p += (size_t)T_TOK * 2 * sizeof(int);
    float* wtok   = (float*)p;               p += (size_t)T_TOK * 2 * sizeof(float);
    int*   rows   = (int*)p;                 p += (size_t)NASSIGN * sizeof(int);
    float* wrow   = (float*)p;               p += (size_t)NASSIGN * sizeof(float);
    unsigned short* act = (unsigned short*)p;  // NASSIGN * IDIM bf16 = 12.6 MB

    hipMemsetAsync(counts, 0, 256, stream);
    hipMemsetAsync(d_out, 0, (size_t)out_size * sizeof(float), stream);

    k_router<<<dim3(T_TOK), dim3(256), 0, stream>>>(x, Wr, bias, wtok, idxtok, counts);
    k_scan<<<dim3(1), dim3(64), 0, stream>>>(counts, offs, cursor);
    k_scatter<<<dim3((T_TOK + 255) / 256), dim3(256), 0, stream>>>(idxtok, wtok, cursor, offs, rows, wrow);
    k_gemm1<<<dim3(32, IDIM / 64, NEX), dim3(256), 0, stream>>>(x, Wg, Wu, sWg, sWu, offs, rows, wrow, act);
    k_gemm2<<<dim3(32, HDIM / 64, NEX), dim3(256), 0, stream>>>(act, Wd, sWd, offs, rows, out);
}

// Round 4
// 367.770 us; speedup vs baseline: 8.0731x; 3.2888x over previous
//
#include <hip/hip_runtime.h>
#include <hip/hip_bf16.h>

#define T_TOK 2048
#define HDIM  2048
#define IDIM  1024
#define NE    16
#define NEX   17                    // 16 routed + 1 shared
#define NASSIGN (T_TOK*3)           // 4096 routed + 2048 shared rows

#define G1_RT 16
#define G1_NCT 8                    // IDIM/128
#define G2_RT 16
#define G2_NCT 16                   // HDIM/128

typedef __attribute__((ext_vector_type(8))) short bf16x8;
typedef __attribute__((ext_vector_type(4))) float f32x4;

__device__ __forceinline__ unsigned short f2bf(float f) {
    union { float f; unsigned u; } v; v.f = f;
    unsigned r = v.u + 0x7fffu + ((v.u >> 16) & 1u);
    return (unsigned short)(r >> 16);
}
__device__ __forceinline__ unsigned pack2f(float a, float b) {
    __hip_bfloat162 h = __float22bfloat162_rn(float2{a, b});
    unsigned r;
    __builtin_memcpy(&r, &h, 4);
    return r;
}
__device__ __forceinline__ float fidx(const float4& v, int j) {
    return ((const float*)&v)[j];
}
// chunk swizzle within 128B LDS rows (rows of 64 bf16)
__device__ __forceinline__ int SW(int r) { return (r ^ (r >> 2)) & 7; }
__device__ __forceinline__ int lds_off(int row, int kelem) {
    return (row << 7) + ((((kelem >> 3) ^ SW(row))) << 4) + ((kelem & 7) << 1);
}
__device__ __forceinline__ f32x4 mfma16(bf16x8 a, bf16x8 b, f32x4 c) {
    return __builtin_amdgcn_mfma_f32_16x16x32_bf16(a, b, c, 0, 0, 0);
}
__device__ __forceinline__ void gload_lds16(const void* g, void* lds) {
    __builtin_amdgcn_global_load_lds(
        (const __attribute__((address_space(1))) unsigned*)g,
        (__attribute__((address_space(3))) unsigned*)lds, 16, 0, 0);
}

// ---------------- x fp32 -> bf16 ----------------
__global__ __launch_bounds__(256) void k_cvt(const float* __restrict__ x,
                                             unsigned short* __restrict__ xbf) {
    int i = blockIdx.x * 256 + threadIdx.x;
    float4 v = ((const float4*)x)[i];
    uint2 p{pack2f(v.x, v.y), pack2f(v.z, v.w)};
    ((uint2*)xbf)[i] = p;
}

// ---------------- Router ----------------
__global__ void k_router(const float* __restrict__ x, const float* __restrict__ Wr,
                         const float* __restrict__ bias, float* __restrict__ wtok,
                         int* __restrict__ idxtok, int* __restrict__ counts) {
    int t = blockIdx.x;
    int lane = threadIdx.x & 63;
    int wave = threadIdx.x >> 6;
    __shared__ float lg[NE];
    const float4* xr = (const float4*)(x + (size_t)t * HDIM);
    for (int e = wave; e < NE; e += 4) {
        const float4* wr = (const float4*)(Wr + (size_t)e * HDIM);
        float s = 0.f;
        for (int j = lane; j < HDIM / 4; j += 64) {
            float4 a = xr[j], b = wr[j];
            s += a.x*b.x + a.y*b.y + a.z*b.z + a.w*b.w;
        }
        #pragma unroll
        for (int d = 32; d; d >>= 1) s += __shfl_xor(s, d);
        if (lane == 0) lg[e] = s + bias[e];
    }
    __syncthreads();
    if (threadIdx.x == 0) {
        float m = lg[0];
        #pragma unroll
        for (int e = 1; e < NE; e++) m = fmaxf(m, lg[e]);
        float p[NE]; float S = 0.f;
        #pragma unroll
        for (int e = 0; e < NE; e++) { p[e] = expf(lg[e] - m); S += p[e]; }
        int i0 = 0;
        #pragma unroll
        for (int e = 1; e < NE; e++) if (p[e] > p[i0]) i0 = e;
        int i1 = (i0 == 0) ? 1 : 0;
        for (int e = 0; e < NE; e++) if (e != i0 && p[e] > p[i1]) i1 = e;
        float v0 = p[i0] / S, v1 = p[i1] / S;
        float wsum = v0 + v1 + 1e-9f;
        wtok[t*2+0] = v0 / wsum;
        wtok[t*2+1] = v1 / wsum;
        idxtok[t*2+0] = i0;
        idxtok[t*2+1] = i1;
        atomicAdd(&counts[i0], 1);
        atomicAdd(&counts[i1], 1);
    }
}

__global__ void k_scan(const int* __restrict__ counts, int* __restrict__ offs,
                       int* __restrict__ cursor) {
    if (threadIdx.x == 0) {
        int acc = 0;
        for (int e = 0; e < NEX; e++) {
            offs[e] = acc; cursor[e] = acc;
            acc += (e < NE) ? counts[e] : T_TOK;
        }
        offs[NEX] = acc;
    }
}

__global__ void k_scatter(const int* __restrict__ idxtok, const float* __restrict__ wtok,
                          int* __restrict__ cursor, const int* __restrict__ offs,
                          int* __restrict__ rows, float* __restrict__ wrow) {
    int t = blockIdx.x * blockDim.x + threadIdx.x;
    if (t >= T_TOK) return;
    #pragma unroll
    for (int k = 0; k < 2; k++) {
        int e = idxtok[t*2+k];
        int pos = atomicAdd(&cursor[e], 1);
        rows[pos] = t;
        wrow[pos] = wtok[t*2+k];
    }
    int p16 = offs[NE] + t;
    rows[p16] = t;
    wrow[p16] = 1.0f;
}

// ---------------- GEMM1: act = w * silu(X@Wg) * (X@Wu) -> bf16 ----------------
// 1-D grid 2176 blocks of 512 thr; tile 128x128, BK=64; XCD-chunked swizzle.
__global__ __launch_bounds__(512) void k_gemm1(
        const unsigned short* __restrict__ xbf,
        const float* __restrict__ Wg, const float* __restrict__ Wu,
        const float* __restrict__ sWg, const float* __restrict__ sWu,
        const int* __restrict__ offs, const int* __restrict__ rows,
        const float* __restrict__ wrow, unsigned short* __restrict__ act) {
    const int nwg = G1_NCT * NEX * G1_RT;            // 2176, %8==0
    int bid = blockIdx.x;
    int wg = (bid & 7) * (nwg >> 3) + (bid >> 3);    // XCD-chunked remap
    int rt = wg & (G1_RT - 1);
    int rest = wg >> 4;                              // ct*NEX + e
    int e = rest % NEX;
    int ct = rest / NEX;

    int rs = offs[e] + rt * 128;
    int re = offs[e + 1];
    if (rs >= re) return;
    int nrows = min(128, re - rs);
    const float* wgp = (e < NE) ? Wg + (size_t)e * HDIM * IDIM : sWg;
    const float* wup = (e < NE) ? Wu + (size_t)e * HDIM * IDIM : sWu;
    int n0 = ct * 128;

    __shared__ unsigned short As[128 * 64];
    __shared__ unsigned short Bs[128 * 64];
    __shared__ unsigned short Us[128 * 64];
    __shared__ int rloc[128];

    int tid = threadIdx.x;
    if (tid < 128) rloc[tid] = rows[rs + min(tid, nrows - 1)];
    __syncthreads();

    int l = tid & 63, w = tid >> 6;
    // A source (pre-swizzled chunk so linear global_load_lds dest matches swizzled reads)
    int ar0 = w * 8 + (l >> 3);
    int ar1 = 64 + ar0;
    int ac = l & 7;
    const unsigned short* asrc0 = xbf + (size_t)rloc[ar0] * HDIM + ((ac ^ SW(ar0)) << 3);
    const unsigned short* asrc1 = xbf + (size_t)rloc[ar1] * HDIM + ((ac ^ SW(ar1)) << 3);

    // B staging coords: 4 consecutive n, 4 consecutive k per thread, per matrix
    int n4 = (tid & 31) << 2;
    int k4 = (tid >> 5) << 2;
    const float* gsrc = wgp + (size_t)k4 * IDIM + n0 + n4;
    const float* usrc = wup + (size_t)k4 * IDIM + n0 + n4;

    int wr = (w >> 2) << 6;          // 0/64
    int wc = (w & 3) << 5;           // 0/32/64/96
    int fr = l & 15;
    int fk = (l >> 4) << 3;

    f32x4 accg[4][2] = {}, accu[4][2] = {};

    for (int k0 = 0; k0 < HDIM; k0 += 64) {
        float4 gv[4], uv[4];
        #pragma unroll
        for (int j = 0; j < 4; ++j) gv[j] = *(const float4*)(gsrc + (size_t)(k0 + j) * IDIM);
        #pragma unroll
        for (int j = 0; j < 4; ++j) uv[j] = *(const float4*)(usrc + (size_t)(k0 + j) * IDIM);

        __syncthreads();             // previous tile consumed
        gload_lds16(asrc0 + k0, (char*)As + w * 1024);
        gload_lds16(asrc1 + k0, (char*)As + 8192 + w * 1024);
        #pragma unroll
        for (int i = 0; i < 4; ++i) {
            int n = n4 + i;
            int off = (n << 7) + ((((k4 >> 3) ^ SW(n))) << 4) + ((k4 & 4) << 1);
            uint2 pg{pack2f(fidx(gv[0], i), fidx(gv[1], i)), pack2f(fidx(gv[2], i), fidx(gv[3], i))};
            uint2 pu{pack2f(fidx(uv[0], i), fidx(uv[1], i)), pack2f(fidx(uv[2], i), fidx(uv[3], i))};
            *(uint2*)((char*)Bs + off) = pg;
            *(uint2*)((char*)Us + off) = pu;
        }
        __syncthreads();             // drains vmcnt(0): A + B ready

        #pragma unroll
        for (int kh = 0; kh < 2; ++kh) {
            int kk = (kh << 5) + fk;
            bf16x8 a[4], bg[2], bu[2];
            #pragma unroll
            for (int m = 0; m < 4; ++m)
                a[m] = *(const bf16x8*)((const char*)As + lds_off(wr + m * 16 + fr, kk));
            #pragma unroll
            for (int n = 0; n < 2; ++n) {
                bg[n] = *(const bf16x8*)((const char*)Bs + lds_off(wc + n * 16 + fr, kk));
                bu[n] = *(const bf16x8*)((const char*)Us + lds_off(wc + n * 16 + fr, kk));
            }
            #pragma unroll
            for (int m = 0; m < 4; ++m) {
                #pragma unroll
                for (int n = 0; n < 2; ++n) {
                    accg[m][n] = mfma16(a[m], bg[n], accg[m][n]);
                    accu[m][n] = mfma16(a[m], bu[n], accu[m][n]);
                }
            }
        }
    }

    int crow = (l >> 4) << 2;
    int ccol = l & 15;
    #pragma unroll
    for (int m = 0; m < 4; ++m) {
        #pragma unroll
        for (int reg = 0; reg < 4; ++reg) {
            int r = wr + m * 16 + crow + reg;
            if (r < nrows) {
                float wv = wrow[rs + r];
                size_t base = (size_t)(rs + r) * IDIM + n0 + wc + ccol;
                #pragma unroll
                for (int n = 0; n < 2; ++n) {
                    float g = accg[m][n][reg], u = accu[m][n][reg];
                    act[base + n * 16] = f2bf(g / (1.f + __expf(-g)) * u * wv);
                }
            }
        }
    }
}

// ---------------- GEMM2: out[tok] += act @ Wd ----------------
__global__ __launch_bounds__(512) void k_gemm2(
        const unsigned short* __restrict__ act,
        const float* __restrict__ Wd, const float* __restrict__ sWd,
        const int* __restrict__ offs, const int* __restrict__ rows,
        float* __restrict__ out) {
    const int nwg = G2_NCT * NEX * G2_RT;            // 4352, %8==0
    int bid = blockIdx.x;
    int wg = (bid & 7) * (nwg >> 3) + (bid >> 3);
    int rt = wg & (G2_RT - 1);
    int rest = wg >> 4;
    int e = rest % NEX;
    int ct = rest / NEX;

    int rs = offs[e] + rt * 128;
    int re = offs[e + 1];
    if (rs >= re) return;
    int nrows = min(128, re - rs);
    const float* wdp = (e < NE) ? Wd + (size_t)e * IDIM * HDIM : sWd;
    int n0 = ct * 128;

    __shared__ unsigned short As[128 * 64];
    __shared__ unsigned short Bs[128 * 64];
    __shared__ int rloc[128];

    int tid = threadIdx.x;
    if (tid < 128) rloc[tid] = rows[rs + min(tid, nrows - 1)];

    int l = tid & 63, w = tid >> 6;
    int ar0 = w * 8 + (l >> 3);
    int ar1 = 64 + ar0;
    int ac = l & 7;
    const unsigned short* asrc0 = act + (size_t)(rs + ar0) * IDIM + ((ac ^ SW(ar0)) << 3);
    const unsigned short* asrc1 = act + (size_t)(rs + ar1) * IDIM + ((ac ^ SW(ar1)) << 3);

    int n4 = (tid & 31) << 2;
    int k4 = (tid >> 5) << 2;
    const float* dsrc = wdp + (size_t)k4 * HDIM + n0 + n4;

    int wr = (w >> 2) << 6;
    int wc = (w & 3) << 5;
    int fr = l & 15;
    int fk = (l >> 4) << 3;

    f32x4 acc[4][2] = {};
    __syncthreads();

    for (int k0 = 0; k0 < IDIM; k0 += 64) {
        float4 dv[4];
        #pragma unroll
        for (int j = 0; j < 4; ++j) dv[j] = *(const float4*)(dsrc + (size_t)(k0 + j) * HDIM);

        __syncthreads();
        gload_lds16(asrc0 + k0, (char*)As + w * 1024);
        gload_lds16(asrc1 + k0, (char*)As + 8192 + w * 1024);
        #pragma unroll
        for (int i = 0; i < 4; ++i) {
            int n = n4 + i;
            int off = (n << 7) + ((((k4 >> 3) ^ SW(n))) << 4) + ((k4 & 4) << 1);
            uint2 pd{pack2f(fidx(dv[0], i), fidx(dv[1], i)), pack2f(fidx(dv[2], i), fidx(dv[3], i))};
            *(uint2*)((char*)Bs + off) = pd;
        }
        __syncthreads();

        #pragma unroll
        for (int kh = 0; kh < 2; ++kh) {
            int kk = (kh << 5) + fk;
            bf16x8 a[4], b[2];
            #pragma unroll
            for (int m = 0; m < 4; ++m)
                a[m] = *(const bf16x8*)((const char*)As + lds_off(wr + m * 16 + fr, kk));
            #pragma unroll
            for (int n = 0; n < 2; ++n)
                b[n] = *(const bf16x8*)((const char*)Bs + lds_off(wc + n * 16 + fr, kk));
            #pragma unroll
            for (int m = 0; m < 4; ++m) {
                #pragma unroll
                for (int n = 0; n < 2; ++n)
                    acc[m][n] = mfma16(a[m], b[n], acc[m][n]);
            }
        }
    }

    int crow = (l >> 4) << 2;
    int ccol = l & 15;
    #pragma unroll
    for (int m = 0; m < 4; ++m) {
        #pragma unroll
        for (int reg = 0; reg < 4; ++reg) {
            int r = wr + m * 16 + crow + reg;
            if (r < nrows) {
                size_t base = (size_t)rloc[r] * HDIM + n0 + wc + ccol;
                atomicAdd(&out[base], acc[m][0][reg]);
                atomicAdd(&out[base + 16], acc[m][1][reg]);
            }
        }
    }
}

extern "C" void kernel_launch(void* const* d_in, const int* in_sizes, int n_in,
                              void* d_out, int out_size, void* d_ws, size_t ws_size,
                              hipStream_t stream) {
    const float* x    = (const float*)d_in[0];
    const float* Wr   = (const float*)d_in[1];
    const float* bias = (const float*)d_in[2];
    const float* Wg   = (const float*)d_in[3];
    const float* Wu   = (const float*)d_in[4];
    const float* Wd   = (const float*)d_in[5];
    const float* sWg  = (const float*)d_in[6];
    const float* sWu  = (const float*)d_in[7];
    const float* sWd  = (const float*)d_in[8];
    float* out = (float*)d_out;

    char* p = (char*)d_ws;
    int*   counts = (int*)p;                 p += 256;
    int*   offs   = (int*)p;                 p += 256;
    int*   cursor = (int*)p;                 p += 256;
    int*   idxtok = (int*)p;                 p += (size_t)T_TOK * 2 * sizeof(int);
    float* wtok   = (float*)p;               p += (size_t)T_TOK * 2 * sizeof(float);
    int*   rows   = (int*)p;                 p += (size_t)NASSIGN * sizeof(int);
    float* wrow   = (float*)p;               p += (size_t)NASSIGN * sizeof(float);
    unsigned short* act = (unsigned short*)p; p += (size_t)NASSIGN * IDIM * sizeof(unsigned short);
    unsigned short* xbf = (unsigned short*)p; // 2048*2048*2 = 8.4MB

    hipMemsetAsync(counts, 0, 256, stream);
    hipMemsetAsync(d_out, 0, (size_t)out_size * sizeof(float), stream);

    k_cvt<<<dim3(T_TOK * HDIM / 1024), dim3(256), 0, stream>>>(x, xbf);
    k_router<<<dim3(T_TOK), dim3(256), 0, stream>>>(x, Wr, bias, wtok, idxtok, counts);
    k_scan<<<dim3(1), dim3(64), 0, stream>>>(counts, offs, cursor);
    k_scatter<<<dim3((T_TOK + 255) / 256), dim3(256), 0, stream>>>(idxtok, wtok, cursor, offs, rows, wrow);
    k_gemm1<<<dim3(G1_NCT * NEX * G1_RT), dim3(512), 0, stream>>>(xbf, Wg, Wu, sWg, sWu, offs, rows, wrow, act);
    k_gemm2<<<dim3(G2_NCT * NEX * G2_RT), dim3(512), 0, stream>>>(act, Wd, sWd, offs, rows, out);
}

// Round 5
// 318.593 us; speedup vs baseline: 9.3192x; 1.1544x over previous
//
#include <hip/hip_runtime.h>
#include <hip/hip_bf16.h>

#define T_TOK 2048
#define HDIM  2048
#define IDIM  1024
#define NE    16
#define NEX   17
#define NASSIGN (T_TOK*3)
#define TM    64                    // max 128-row tiles (<= 48 routed + 16 shared)

#define G1_NCT 16                   // IDIM/64
#define G2_NCT 32                   // HDIM/64
#define G1_NWG (TM*G1_NCT)          // 1024
#define G2_NWG (TM*G2_NCT)          // 2048

typedef __attribute__((ext_vector_type(8))) short bf16x8;
typedef __attribute__((ext_vector_type(4))) float f32x4;

__device__ __forceinline__ unsigned short f2bf(float f) {
    union { float f; unsigned u; } v; v.f = f;
    unsigned r = v.u + 0x7fffu + ((v.u >> 16) & 1u);
    return (unsigned short)(r >> 16);
}
__device__ __forceinline__ unsigned pack2f(float a, float b) {
    __hip_bfloat162 h = __float22bfloat162_rn(float2{a, b});
    unsigned r;
    __builtin_memcpy(&r, &h, 4);
    return r;
}
__device__ __forceinline__ float fidx(const float4& v, int j) {
    return ((const float*)&v)[j];
}
// chunk swizzle within 128B LDS rows (rows of 64 bf16)
__device__ __forceinline__ int SW(int r) { return (r ^ (r >> 2)) & 7; }
__device__ __forceinline__ int lds_off(int row, int kelem) {
    return (row << 7) + ((((kelem >> 3) ^ SW(row))) << 4) + ((kelem & 7) << 1);
}
__device__ __forceinline__ f32x4 mfma16(bf16x8 a, bf16x8 b, f32x4 c) {
    return __builtin_amdgcn_mfma_f32_16x16x32_bf16(a, b, c, 0, 0, 0);
}

// ---------------- x fp32 -> bf16 ----------------
__global__ __launch_bounds__(256) void k_cvt(const float* __restrict__ x,
                                             unsigned short* __restrict__ xbf) {
    int i = blockIdx.x * 256 + threadIdx.x;
    float4 v = ((const float4*)x)[i];
    uint2 p{pack2f(v.x, v.y), pack2f(v.z, v.w)};
    ((uint2*)xbf)[i] = p;
}

// ---------------- Router ----------------
__global__ void k_router(const float* __restrict__ x, const float* __restrict__ Wr,
                         const float* __restrict__ bias, float* __restrict__ wtok,
                         int* __restrict__ idxtok, int* __restrict__ counts) {
    int t = blockIdx.x;
    int lane = threadIdx.x & 63;
    int wave = threadIdx.x >> 6;
    __shared__ float lg[NE];
    const float4* xr = (const float4*)(x + (size_t)t * HDIM);
    for (int e = wave; e < NE; e += 4) {
        const float4* wr = (const float4*)(Wr + (size_t)e * HDIM);
        float s = 0.f;
        for (int j = lane; j < HDIM / 4; j += 64) {
            float4 a = xr[j], b = wr[j];
            s += a.x*b.x + a.y*b.y + a.z*b.z + a.w*b.w;
        }
        #pragma unroll
        for (int d = 32; d; d >>= 1) s += __shfl_xor(s, d);
        if (lane == 0) lg[e] = s + bias[e];
    }
    __syncthreads();
    if (threadIdx.x == 0) {
        float m = lg[0];
        #pragma unroll
        for (int e = 1; e < NE; e++) m = fmaxf(m, lg[e]);
        float p[NE]; float S = 0.f;
        #pragma unroll
        for (int e = 0; e < NE; e++) { p[e] = expf(lg[e] - m); S += p[e]; }
        int i0 = 0;
        #pragma unroll
        for (int e = 1; e < NE; e++) if (p[e] > p[i0]) i0 = e;
        int i1 = (i0 == 0) ? 1 : 0;
        for (int e = 0; e < NE; e++) if (e != i0 && p[e] > p[i1]) i1 = e;
        float v0 = p[i0] / S, v1 = p[i1] / S;
        float wsum = v0 + v1 + 1e-9f;
        wtok[t*2+0] = v0 / wsum;
        wtok[t*2+1] = v1 / wsum;
        idxtok[t*2+0] = i0;
        idxtok[t*2+1] = i1;
        atomicAdd(&counts[i0], 1);
        atomicAdd(&counts[i1], 1);
    }
}

// ---------------- scan + tile work-list ----------------
__global__ void k_scan(const int* __restrict__ counts, int* __restrict__ offs,
                       int* __restrict__ cursor, int4* __restrict__ tiles) {
    if (threadIdx.x == 0) {
        int acc = 0;
        for (int e = 0; e < NEX; e++) {
            offs[e] = acc; cursor[e] = acc;
            acc += (e < NE) ? counts[e] : T_TOK;
        }
        offs[NEX] = acc;
        int nt = 0;
        for (int e = 0; e < NEX; e++) {
            for (int r = offs[e]; r < offs[e+1]; r += 128) {
                tiles[nt] = int4{r, min(128, offs[e+1] - r), e, 0};
                nt++;
            }
        }
        for (; nt < TM; nt++) tiles[nt] = int4{0, 0, 0, 0};
    }
}

__global__ void k_scatter(const int* __restrict__ idxtok, const float* __restrict__ wtok,
                          int* __restrict__ cursor, const int* __restrict__ offs,
                          int* __restrict__ rows, float* __restrict__ wrow) {
    int t = blockIdx.x * blockDim.x + threadIdx.x;
    if (t >= T_TOK) return;
    #pragma unroll
    for (int k = 0; k < 2; k++) {
        int e = idxtok[t*2+k];
        int pos = atomicAdd(&cursor[e], 1);
        rows[pos] = t;
        wrow[pos] = wtok[t*2+k];
    }
    int p16 = offs[NE] + t;
    rows[p16] = t;
    wrow[p16] = 1.0f;
}

// ---------------- GEMM1: act = w * silu(X@Wg) * (X@Wu) -> bf16 ----------------
// tile 128 rows x 64 cols, BK=64, 512 thr (8 waves 2x4), LDS double-buffered,
// single barrier per K-step, one-step register prefetch.
__global__ __launch_bounds__(512) void k_gemm1(
        const unsigned short* __restrict__ xbf,
        const float* __restrict__ Wg, const float* __restrict__ Wu,
        const float* __restrict__ sWg, const float* __restrict__ sWu,
        const int4* __restrict__ tiles, const int* __restrict__ rows,
        const float* __restrict__ wrow, unsigned short* __restrict__ act) {
    int bid = blockIdx.x;
    int wg = (bid & 7) * (G1_NWG >> 3) + (bid >> 3);   // XCD-chunked
    int ti = wg & (TM - 1);
    int ct = wg >> 6;

    int4 tl = tiles[ti];
    int nrows = tl.y;
    if (nrows == 0) return;
    int rs = tl.x, e = tl.z;
    const float* wgp = (e < NE) ? Wg + (size_t)e * HDIM * IDIM : sWg;
    const float* wup = (e < NE) ? Wu + (size_t)e * HDIM * IDIM : sWu;
    int n0 = ct * 64;

    __shared__ unsigned short As[2][128 * 64];
    __shared__ unsigned short Bs[2][64 * 64];
    __shared__ unsigned short Us[2][64 * 64];
    __shared__ int rloc[128];

    int tid = threadIdx.x;
    if (tid < 128) rloc[tid] = rows[rs + min(tid, nrows - 1)];
    __syncthreads();

    // staging coords
    int arow = tid >> 2;
    int akc  = (tid & 3) << 4;                         // 0,16,32,48
    const unsigned short* asrc = xbf + (size_t)rloc[arow] * HDIM + akc;
    int n4 = (tid & 15) << 2;
    int kb = (tid >> 4) << 1;                          // 0..62 step 2
    const float* gsrc = wgp + (size_t)kb * IDIM + n0 + n4;
    const float* usrc = wup + (size_t)kb * IDIM + n0 + n4;

    int l = tid & 63, w = tid >> 6;
    int wr = (w >> 2) << 6;                            // 0/64
    int wc = (w & 3) << 4;                             // 0/16/32/48
    int fr = l & 15;
    int fk = (l >> 4) << 3;

    uint4 aR0, aR1;
    float4 gR0, gR1, uR0, uR1;

    #define G1_LOAD(K0) do { \
        aR0 = *(const uint4*)(asrc + (K0)); \
        aR1 = *(const uint4*)(asrc + (K0) + 8); \
        gR0 = *(const float4*)(gsrc + (size_t)(K0) * IDIM); \
        gR1 = *(const float4*)(gsrc + (size_t)(K0) * IDIM + IDIM); \
        uR0 = *(const float4*)(usrc + (size_t)(K0) * IDIM); \
        uR1 = *(const float4*)(usrc + (size_t)(K0) * IDIM + IDIM); \
    } while (0)

    #define G1_WRITE(B) do { \
        *(uint4*)((char*)As[B] + lds_off(arow, akc))     = aR0; \
        *(uint4*)((char*)As[B] + lds_off(arow, akc + 8)) = aR1; \
        _Pragma("unroll") \
        for (int i = 0; i < 4; ++i) { \
            int n = n4 + i; \
            *(unsigned*)((char*)Bs[B] + lds_off(n, kb)) = pack2f(fidx(gR0,i), fidx(gR1,i)); \
            *(unsigned*)((char*)Us[B] + lds_off(n, kb)) = pack2f(fidx(uR0,i), fidx(uR1,i)); \
        } \
    } while (0)

    f32x4 accg[4] = {}, accu[4] = {};
    const int NK = HDIM / 64;

    G1_LOAD(0);
    G1_WRITE(0);
    G1_LOAD(64);
    __syncthreads();

    for (int k = 0; k < NK; ++k) {
        int buf = k & 1;
        #pragma unroll
        for (int kh = 0; kh < 2; ++kh) {
            int kk = (kh << 5) + fk;
            bf16x8 a[4], bg, bu;
            #pragma unroll
            for (int m = 0; m < 4; ++m)
                a[m] = *(const bf16x8*)((const char*)As[buf] + lds_off(wr + m * 16 + fr, kk));
            bg = *(const bf16x8*)((const char*)Bs[buf] + lds_off(wc + fr, kk));
            bu = *(const bf16x8*)((const char*)Us[buf] + lds_off(wc + fr, kk));
            #pragma unroll
            for (int m = 0; m < 4; ++m) {
                accg[m] = mfma16(a[m], bg, accg[m]);
                accu[m] = mfma16(a[m], bu, accu[m]);
            }
        }
        if (k + 1 < NK) {
            G1_WRITE(buf ^ 1);
            if (k + 2 < NK) G1_LOAD((k + 2) * 64);
            __syncthreads();
        }
    }

    int crow = (l >> 4) << 2;
    int ccol = l & 15;
    #pragma unroll
    for (int m = 0; m < 4; ++m) {
        #pragma unroll
        for (int reg = 0; reg < 4; ++reg) {
            int r = wr + m * 16 + crow + reg;
            if (r < nrows) {
                float wv = wrow[rs + r];
                float g = accg[m][reg], u = accu[m][reg];
                act[(size_t)(rs + r) * IDIM + n0 + wc + ccol] =
                    f2bf(g / (1.f + __expf(-g)) * u * wv);
            }
        }
    }
}

// ---------------- GEMM2: out[tok] += act @ Wd ----------------
__global__ __launch_bounds__(512) void k_gemm2(
        const unsigned short* __restrict__ act,
        const float* __restrict__ Wd, const float* __restrict__ sWd,
        const int4* __restrict__ tiles, const int* __restrict__ rows,
        float* __restrict__ out) {
    int bid = blockIdx.x;
    int wg = (bid & 7) * (G2_NWG >> 3) + (bid >> 3);
    int ti = wg & (TM - 1);
    int ct = wg >> 6;

    int4 tl = tiles[ti];
    int nrows = tl.y;
    if (nrows == 0) return;
    int rs = tl.x, e = tl.z;
    const float* wdp = (e < NE) ? Wd + (size_t)e * IDIM * HDIM : sWd;
    int n0 = ct * 64;

    __shared__ unsigned short As[2][128 * 64];
    __shared__ unsigned short Bs[2][64 * 64];
    __shared__ int rloc[128];

    int tid = threadIdx.x;
    if (tid < 128) rloc[tid] = rows[rs + min(tid, nrows - 1)];
    __syncthreads();

    int arow = tid >> 2;
    int akc  = (tid & 3) << 4;
    const unsigned short* asrc = act + (size_t)(rs + min(arow, nrows - 1)) * IDIM + akc;
    int n4 = (tid & 15) << 2;
    int kb = (tid >> 4) << 1;
    const float* dsrc = wdp + (size_t)kb * HDIM + n0 + n4;

    int l = tid & 63, w = tid >> 6;
    int wr = (w >> 2) << 6;
    int wc = (w & 3) << 4;
    int fr = l & 15;
    int fk = (l >> 4) << 3;

    uint4 aR0, aR1;
    float4 dR0, dR1;

    #define G2_LOAD(K0) do { \
        aR0 = *(const uint4*)(asrc + (K0)); \
        aR1 = *(const uint4*)(asrc + (K0) + 8); \
        dR0 = *(const float4*)(dsrc + (size_t)(K0) * HDIM); \
        dR1 = *(const float4*)(dsrc + (size_t)(K0) * HDIM + HDIM); \
    } while (0)

    #define G2_WRITE(B) do { \
        *(uint4*)((char*)As[B] + lds_off(arow, akc))     = aR0; \
        *(uint4*)((char*)As[B] + lds_off(arow, akc + 8)) = aR1; \
        _Pragma("unroll") \
        for (int i = 0; i < 4; ++i) { \
            int n = n4 + i; \
            *(unsigned*)((char*)Bs[B] + lds_off(n, kb)) = pack2f(fidx(dR0,i), fidx(dR1,i)); \
        } \
    } while (0)

    f32x4 acc[4] = {};
    const int NK = IDIM / 64;

    G2_LOAD(0);
    G2_WRITE(0);
    G2_LOAD(64);
    __syncthreads();

    for (int k = 0; k < NK; ++k) {
        int buf = k & 1;
        #pragma unroll
        for (int kh = 0; kh < 2; ++kh) {
            int kk = (kh << 5) + fk;
            bf16x8 a[4], b;
            #pragma unroll
            for (int m = 0; m < 4; ++m)
                a[m] = *(const bf16x8*)((const char*)As[buf] + lds_off(wr + m * 16 + fr, kk));
            b = *(const bf16x8*)((const char*)Bs[buf] + lds_off(wc + fr, kk));
            #pragma unroll
            for (int m = 0; m < 4; ++m)
                acc[m] = mfma16(a[m], b, acc[m]);
        }
        if (k + 1 < NK) {
            G2_WRITE(buf ^ 1);
            if (k + 2 < NK) G2_LOAD((k + 2) * 64);
            __syncthreads();
        }
    }

    int crow = (l >> 4) << 2;
    int ccol = l & 15;
    #pragma unroll
    for (int m = 0; m < 4; ++m) {
        #pragma unroll
        for (int reg = 0; reg < 4; ++reg) {
            int r = wr + m * 16 + crow + reg;
            if (r < nrows) {
                atomicAdd(&out[(size_t)rloc[r] * HDIM + n0 + wc + ccol], acc[m][reg]);
            }
        }
    }
}

extern "C" void kernel_launch(void* const* d_in, const int* in_sizes, int n_in,
                              void* d_out, int out_size, void* d_ws, size_t ws_size,
                              hipStream_t stream) {
    const float* x    = (const float*)d_in[0];
    const float* Wr   = (const float*)d_in[1];
    const float* bias = (const float*)d_in[2];
    const float* Wg   = (const float*)d_in[3];
    const float* Wu   = (const float*)d_in[4];
    const float* Wd   = (const float*)d_in[5];
    const float* sWg  = (const float*)d_in[6];
    const float* sWu  = (const float*)d_in[7];
    const float* sWd  = (const float*)d_in[8];
    float* out = (float*)d_out;

    char* p = (char*)d_ws;
    int*   counts = (int*)p;                 p += 256;
    int*   offs   = (int*)p;                 p += 256;
    int*   cursor = (int*)p;                 p += 256;
    int4*  tiles  = (int4*)p;                p += TM * sizeof(int4);
    int*   idxtok = (int*)p;                 p += (size_t)T_TOK * 2 * sizeof(int);
    float* wtok   = (float*)p;               p += (size_t)T_TOK * 2 * sizeof(float);
    int*   rows   = (int*)p;                 p += (size_t)NASSIGN * sizeof(int);
    float* wrow   = (float*)p;               p += (size_t)NASSIGN * sizeof(float);
    unsigned short* act = (unsigned short*)p; p += (size_t)NASSIGN * IDIM * sizeof(unsigned short);
    unsigned short* xbf = (unsigned short*)p; // 8.4MB

    hipMemsetAsync(counts, 0, 256, stream);
    hipMemsetAsync(d_out, 0, (size_t)out_size * sizeof(float), stream);

    k_cvt<<<dim3(T_TOK * HDIM / 1024), dim3(256), 0, stream>>>(x, xbf);
    k_router<<<dim3(T_TOK), dim3(256), 0, stream>>>(x, Wr, bias, wtok, idxtok, counts);
    k_scan<<<dim3(1), dim3(64), 0, stream>>>(counts, offs, cursor, tiles);
    k_scatter<<<dim3((T_TOK + 255) / 256), dim3(256), 0, stream>>>(idxtok, wtok, cursor, offs, rows, wrow);
    k_gemm1<<<dim3(G1_NWG), dim3(512), 0, stream>>>(xbf, Wg, Wu, sWg, sWu, tiles, rows, wrow, act);
    k_gemm2<<<dim3(G2_NWG), dim3(512), 0, stream>>>(act, Wd, sWd, tiles, rows, out);
}